// Round 1
// baseline (29966.055 us; speedup 1.0000x reference)
//
#include <hip/hip_runtime.h>
#include <hip/hip_bf16.h>

#define DEPTH 24
#define DM 192
#define DI 384
#define DS 16
#define DR 12
#define LSEQ 401
#define BATCH 4
#define NTOK (BATCH*LSEQ)          // 1604
#define NCLS 22
#define NC 16                      // scan time-chunks
#define TCH 26                     // ceil(401/16); last chunk = 11

// persistent-kernel geometry
#define NBLK 768                   // 3 blocks/CU guaranteed by __launch_bounds__(256,3)
#define NSLOT 144                  // 6 grid syncs per layer * 24 layers
#define SLOT_WORDS (34*32)         // 32 padded leaf counters + root + done (one 128B line each)
#define BARS_WORDS (NSLOT*SLOT_WORDS)

__device__ __forceinline__ float silu_f(float x) { return x / (1.f + __expf(-x)); }

// ---------------- LDS union shared by all stages (max member 31,104 B) ----------------
union SMem {
    struct { float As[48][68]; float Ws[48][68]; } gx;                      // 26112 B
    struct { float As[96][33]; float Ws[96][48]; } xp;                      // 31104 B
    struct { float sdbl[TCH][44]; float sdt[TCH][16]; float sxx[TCH][16];
             float sy[TCH][16]; float sw[16][12]; float sb2[16]; } sc;      // 10400 B
    struct { float As[48][34]; float Ws[48][34]; } op;                      // 13056 B
    struct { float hb[DM]; float wsum[4]; } fh;                             //   784 B
};

// ---------------- device-scope two-level grid barrier ----------------
// slot layout (words): [leaf*32] for leaf 0..31, [32*32]=root, [33*32]=done
__device__ __forceinline__ void gsync(unsigned* __restrict__ bars, int slot)
{
    __syncthreads();
    if (threadIdx.x == 0) {
        unsigned* base = bars + (size_t)slot * SLOT_WORDS;
        int leaf = blockIdx.x & 31;                  // NBLK/32 = 24 blocks per leaf
        __threadfence();                             // publish this block's global writes
        unsigned v = __hip_atomic_fetch_add(base + leaf * 32, 1u,
                                            __ATOMIC_ACQ_REL, __HIP_MEMORY_SCOPE_AGENT);
        if (v == (NBLK / 32) - 1) {
            unsigned r = __hip_atomic_fetch_add(base + 32 * 32, 1u,
                                                __ATOMIC_ACQ_REL, __HIP_MEMORY_SCOPE_AGENT);
            if (r == 31)
                __hip_atomic_store(base + 33 * 32, 1u,
                                   __ATOMIC_RELEASE, __HIP_MEMORY_SCOPE_AGENT);
        }
        while (__hip_atomic_load(base + 33 * 32,
                                 __ATOMIC_ACQUIRE, __HIP_MEMORY_SCOPE_AGENT) == 0u)
            __builtin_amdgcn_s_sleep(2);
    }
    __syncthreads();
}

// ---------------- patch embed + cls + pos; 4 tokens per block; also zeroes barrier slots ----------------
__global__ void patch_embed_k(const float* __restrict__ x,
                              const float* __restrict__ pe_w,
                              const float* __restrict__ pe_b,
                              const float* __restrict__ cls,
                              const float* __restrict__ pos,
                              float* __restrict__ residual, float* __restrict__ hidden,
                              unsigned* __restrict__ bars)
{
    // zero the grid-barrier slots for the persistent kernel that follows
    for (int i = blockIdx.x * 192 + threadIdx.x; i < BARS_WORDS; i += 401 * 192)
        bars[i] = 0u;

    __shared__ float xp[4][256];
    int g0 = blockIdx.x * 4;
    int c = threadIdx.x;                  // 0..191
    #pragma unroll
    for (int j = 0; j < 4; j++) {
        int g = g0 + j;
        int b = g / LSEQ, t = g % LSEQ;
        if (t != 0) {
            int p = t - 1, pi = p / 200, pj = p % 200;
            for (int i = c; i < 256; i += 192) {
                int pp = i >> 4, qq = i & 15;
                xp[j][i] = x[((size_t)(b * 32 + pi * 16 + pp)) * 3200 + pj * 16 + qq];
            }
        }
    }
    __syncthreads();
    float acc[4] = {0.f, 0.f, 0.f, 0.f};
    for (int k = 0; k < 256; k++) {
        float w = pe_w[c * 256 + k];
        #pragma unroll
        for (int j = 0; j < 4; j++) acc[j] += xp[j][k] * w;
    }
    #pragma unroll
    for (int j = 0; j < 4; j++) {
        int g = g0 + j;
        int t = g % LSEQ;
        float v = (t == 0) ? cls[c] : (acc[j] + pe_b[c]);
        v += pos[t * DM + c];
        residual[(size_t)g * DM + c] = v;
        hidden[(size_t)g * DM + c] = v;
    }
}

// ================= stage device functions (virtual-block versions) =================

// prenorm: one wave per token (192ch = 3/lane); also zeroes dbl for xproj atomics.
__device__ void st_prenorm(int vb,
    const float* __restrict__ resin, const float* __restrict__ hidden,
    float* __restrict__ resout, float* __restrict__ hnorm,
    const float* __restrict__ nw, float* __restrict__ dbl)
{
    int wave = threadIdx.x >> 6, lane = threadIdx.x & 63;
    int t = vb * 4 + wave;                       // covers 3072 >= 1604
    if (t < NTOK) {
        size_t base = (size_t)t * DM;
        int c0 = lane, c1 = lane + 64, c2 = lane + 128;
        float r0 = resin[base + c0] + hidden[base + c0];
        float r1 = resin[base + c1] + hidden[base + c1];
        float r2 = resin[base + c2] + hidden[base + c2];
        float s = r0 * r0 + r1 * r1 + r2 * r2;
        #pragma unroll
        for (int off = 32; off; off >>= 1) s += __shfl_xor(s, off);
        float rms = rsqrtf(s * (1.f / (float)DM) + 1e-5f);
        resout[base + c0] = r0; resout[base + c1] = r1; resout[base + c2] = r2;
        hnorm[base + c0] = r0 * rms * nw[c0];
        hnorm[base + c1] = r1 * rms * nw[c1];
        hnorm[base + c2] = r2 * rms * nw[c2];
    }
    for (int i = vb * 256 + threadIdx.x; i < 2 * NTOK * 44; i += NBLK * 256)
        dbl[i] = 0.f;
}

// xz GEMM: xz = hnorm @ ipw^T. 64x64 tile, 4x4/thread, KS=48. virtual grid 12x26=312.
__device__ void st_gemm_xz(int vb, SMem& sm,
    const float* __restrict__ hnorm, const float* __restrict__ ipw,
    float* __restrict__ xz)
{
    if (vb >= 312) return;
    constexpr int KS = 48;
    int tid = threadIdx.x;
    int bn = (vb % 12) * 64;
    int bm = (vb / 12) * 64;
    int r0 = (tid >> 4) * 4;
    int c0 = (tid & 15) * 4;
    int srow = tid >> 2, sk = (tid & 3) * 12;
    float acc[4][4] = {};
    for (int k0 = 0; k0 < DM; k0 += KS) {
        {
            int m = bm + srow;
            const float* ap = hnorm + (size_t)m * DM + k0 + sk;
            #pragma unroll
            for (int i = 0; i < 12; i++)
                sm.gx.As[sk + i][srow] = (m < NTOK) ? ap[i] : 0.f;
            const float* wp = ipw + (size_t)(bn + srow) * DM + k0 + sk;
            #pragma unroll
            for (int i = 0; i < 12; i++)
                sm.gx.Ws[sk + i][srow] = wp[i];
        }
        __syncthreads();
        #pragma unroll
        for (int kk = 0; kk < KS; kk++) {
            float4 a = *(const float4*)&sm.gx.As[kk][r0];
            float4 w = *(const float4*)&sm.gx.Ws[kk][c0];
            acc[0][0] += a.x * w.x; acc[0][1] += a.x * w.y; acc[0][2] += a.x * w.z; acc[0][3] += a.x * w.w;
            acc[1][0] += a.y * w.x; acc[1][1] += a.y * w.y; acc[1][2] += a.y * w.z; acc[1][3] += a.y * w.w;
            acc[2][0] += a.z * w.x; acc[2][1] += a.z * w.y; acc[2][2] += a.z * w.z; acc[2][3] += a.z * w.w;
            acc[3][0] += a.w * w.x; acc[3][1] += a.w * w.y; acc[3][2] += a.w * w.z; acc[3][3] += a.w * w.w;
        }
        __syncthreads();
    }
    #pragma unroll
    for (int i = 0; i < 4; i++) {
        int m = bm + r0 + i;
        if (m >= NTOK) continue;
        *(float4*)&xz[(size_t)m * (2 * DI) + bn + c0] =
            make_float4(acc[i][0], acc[i][1], acc[i][2], acc[i][3]);
    }
}

// xproj with conv fused: dbl += silu(conv(xz)) @ xpw^T, split-K=4. virtual grid 4x101=404.
__device__ void st_xproj(int vb, SMem& sm,
    const float* __restrict__ xz,
    const float* __restrict__ cw, const float* __restrict__ cb,
    const float* __restrict__ xpw, float* __restrict__ dbl)
{
    if (vb >= 404) return;
    int tid = threadIdx.x;
    int kbase = (vb & 3) * 96;
    int bm = (vb >> 2) * 32;
    for (int idx = tid; idx < 96 * 32; idx += 256) {
        int k = idx >> 5, row = idx & 31;
        int m = bm + row;
        float v = 0.f;
        if (m < 2 * NTOK) {
            int dir = m / NTOK;
            int r = m - dir * NTOK;
            int b = r / LSEQ, t = r % LSEQ;
            int ch = kbase + k;
            float a = cb[ch];
            #pragma unroll
            for (int j = 0; j < 4; j++) {
                int tt = t - 3 + j;
                if (tt >= 0) {
                    int st = dir ? (LSEQ - 1 - tt) : tt;
                    a += cw[ch * 4 + j] * xz[((size_t)(b * LSEQ + st)) * (2 * DI) + ch];
                }
            }
            v = silu_f(a);
        }
        sm.xp.As[k][row] = v;
    }
    for (int i = tid; i < 96 * 48; i += 256) {
        int k = i / 48, rr = i % 48;
        sm.xp.Ws[k][rr] = (rr < 44) ? xpw[(size_t)rr * DI + kbase + k] : 0.f;
    }
    __syncthreads();
    int row = tid & 31, cg = tid >> 5;
    int cbase = cg * 6;
    float acc[6] = {};
    #pragma unroll 4
    for (int kk = 0; kk < 96; kk++) {
        float a = sm.xp.As[kk][row];
        #pragma unroll
        for (int j = 0; j < 6; j++) acc[j] += a * sm.xp.Ws[kk][cbase + j];
    }
    int m = bm + row;
    if (m < 2 * NTOK) {
        #pragma unroll
        for (int j = 0; j < 6; j++) {
            int cc = cbase + j;
            if (cc < 44) atomicAdd(&dbl[(size_t)m * 44 + cc], acc[j]);
        }
    }
}

// scan pass 1: conv+dt staging, local scan + chunk product. virtual grid 24x15x8=2880.
__device__ void st_scan_part(int vb0, SMem& sm,
    const float* __restrict__ xz, const float* __restrict__ dbl,
    const float* __restrict__ cw, const float* __restrict__ cb,
    const float* __restrict__ dtw, const float* __restrict__ dtb,
    const float* __restrict__ A_log, const float* __restrict__ A_b_log,
    float* __restrict__ hloc, float* __restrict__ Pc)
{
    int tid = threadIdx.x;
    for (int v = vb0; v < 24 * (NC - 1) * 8; v += NBLK) {
        int dblk = v % 24;
        int rem = v / 24;
        int chunk = rem % (NC - 1);
        int db = rem / (NC - 1);
        int dir = db >> 2, b = db & 3;
        int d0 = dblk * 16;
        int t0 = chunk * TCH;
        size_t dof44 = (size_t)db * LSEQ * 44;
        for (int i = tid; i < TCH * 44; i += 256) {
            int t = i / 44, cc = i - t * 44;
            sm.sc.sdbl[t][cc] = dbl[dof44 + (size_t)(t0 + t) * 44 + cc];
        }
        if (tid < 192) { int d = tid / 12, r = tid - d * 12; sm.sc.sw[d][r] = dtw[(size_t)(d0 + d) * 12 + r]; }
        if (tid < 16) sm.sc.sb2[tid] = dtb[d0 + tid];
        for (int i = tid; i < TCH * 16; i += 256) {
            int t = i >> 4, d = i & 15;
            int tq = t0 + t, ch = d0 + d;
            float a = cb[ch];
            #pragma unroll
            for (int j = 0; j < 4; j++) {
                int tt = tq - 3 + j;
                if (tt >= 0) {
                    int st = dir ? (LSEQ - 1 - tt) : tt;
                    a += cw[ch * 4 + j] * xz[((size_t)(b * LSEQ + st)) * (2 * DI) + ch];
                }
            }
            sm.sc.sxx[t][d] = silu_f(a);
        }
        __syncthreads();
        for (int i = tid; i < TCH * 16; i += 256) {
            int t = i >> 4, d = i & 15;
            float a2 = sm.sc.sb2[d];
            #pragma unroll
            for (int r = 0; r < 12; r++) a2 += sm.sc.sdbl[t][r] * sm.sc.sw[d][r];
            sm.sc.sdt[t][d] = (a2 > 15.f) ? a2 : __logf(1.f + __expf(a2));
        }
        __syncthreads();
        int wave = tid >> 6, lane = tid & 63;
        int dsub = wave * 4 + (lane >> 4);
        int n = lane & 15;
        const float* Al = dir ? A_b_log : A_log;
        float Aval = -__expf(Al[(d0 + dsub) * DS + n]);
        float h = 0.f, P = 1.f;
        #pragma unroll
        for (int i = 0; i < TCH; i++) {
            float dtv = sm.sc.sdt[i][dsub];
            float xv  = sm.sc.sxx[i][dsub];
            float Bv  = sm.sc.sdbl[i][12 + n];
            float dA = __expf(dtv * Aval);
            h = dA * h + (dtv * xv) * Bv;
            P *= dA;
        }
        size_t idx2 = ((size_t)db * NC + chunk) * (DI * DS) + (size_t)(d0 + dsub) * DS + n;
        hloc[idx2] = h;
        Pc[idx2] = P;
        __syncthreads();   // LDS reused by next virtual block
    }
}

// scan pass 2: compose h_init, rescan, emit y. virtual grid 24x16x8=3072 (= 4*NBLK exactly).
__device__ void st_scan_fix(int vb0, SMem& sm,
    const float* __restrict__ xz, const float* __restrict__ dbl,
    const float* __restrict__ cw, const float* __restrict__ cb,
    const float* __restrict__ dtw, const float* __restrict__ dtb,
    const float* __restrict__ A_log, const float* __restrict__ A_b_log,
    const float* __restrict__ Dp,
    const float* __restrict__ hloc, const float* __restrict__ Pc,
    float* __restrict__ yraw)
{
    int tid = threadIdx.x;
    for (int v = vb0; v < 24 * NC * 8; v += NBLK) {
        int dblk = v % 24;
        int rem = v / 24;
        int chunk = rem % NC;
        int db = rem / NC;
        int dir = db >> 2, b = db & 3;
        int d0 = dblk * 16;
        int t0 = chunk * TCH;
        size_t dofD = (size_t)db * LSEQ * DI;
        size_t dof44 = (size_t)db * LSEQ * 44;
        for (int i = tid; i < TCH * 44; i += 256) {
            int t = i / 44, cc = i - t * 44;
            sm.sc.sdbl[t][cc] = ((t0 + t) < LSEQ) ? dbl[dof44 + (size_t)(t0 + t) * 44 + cc] : 0.f;
        }
        if (tid < 192) { int d = tid / 12, r = tid - d * 12; sm.sc.sw[d][r] = dtw[(size_t)(d0 + d) * 12 + r]; }
        if (tid < 16) sm.sc.sb2[tid] = dtb[d0 + tid];
        for (int i = tid; i < TCH * 16; i += 256) {
            int t = i >> 4, d = i & 15;
            int tq = t0 + t, ch = d0 + d;
            float vv = 0.f;
            if (tq < LSEQ) {
                float a = cb[ch];
                #pragma unroll
                for (int j = 0; j < 4; j++) {
                    int tt = tq - 3 + j;
                    if (tt >= 0) {
                        int st = dir ? (LSEQ - 1 - tt) : tt;
                        a += cw[ch * 4 + j] * xz[((size_t)(b * LSEQ + st)) * (2 * DI) + ch];
                    }
                }
                vv = silu_f(a);
            }
            sm.sc.sxx[t][d] = vv;
        }
        __syncthreads();
        for (int i = tid; i < TCH * 16; i += 256) {
            int t = i >> 4, d = i & 15;
            float a2 = sm.sc.sb2[d];
            #pragma unroll
            for (int r = 0; r < 12; r++) a2 += sm.sc.sdbl[t][r] * sm.sc.sw[d][r];
            sm.sc.sdt[t][d] = (a2 > 15.f) ? a2 : __logf(1.f + __expf(a2));
        }
        __syncthreads();
        int wave = tid >> 6, lane = tid & 63;
        int dsub = wave * 4 + (lane >> 4);
        int n = lane & 15;
        const float* Al = dir ? A_b_log : A_log;
        float Aval = -__expf(Al[(d0 + dsub) * DS + n]);
        float Dv = Dp[d0 + dsub];
        float h = 0.f;
        size_t cbase = (size_t)db * NC * (DI * DS) + (size_t)(d0 + dsub) * DS + n;
        #pragma unroll
        for (int j = 0; j < NC - 1; j++) {
            size_t idx = cbase + (size_t)j * (DI * DS);
            float pj = Pc[idx], hj = hloc[idx];
            h = (j < chunk) ? (pj * h + hj) : h;
        }
        #pragma unroll
        for (int i = 0; i < TCH; i++) {
            float dtv = sm.sc.sdt[i][dsub];
            float xv  = sm.sc.sxx[i][dsub];
            float Bv  = sm.sc.sdbl[i][12 + n];
            float Cv  = sm.sc.sdbl[i][28 + n];
            h = __expf(dtv * Aval) * h + (dtv * xv) * Bv;
            float p = h * Cv;
            p += __shfl_xor(p, 1);
            p += __shfl_xor(p, 2);
            p += __shfl_xor(p, 4);
            p += __shfl_xor(p, 8);
            if (n == 0) sm.sc.sy[i][dsub] = p + xv * Dv;
        }
        __syncthreads();
        int len = min(t0 + TCH, LSEQ) - t0;
        for (int idx = tid; idx < len * 16; idx += 256) {
            int t = idx >> 4, d = idx & 15;
            yraw[dofD + (size_t)(t0 + t) * DI + d0 + d] = sm.sc.sy[t][d];
        }
        __syncthreads();   // LDS reused by next virtual block
    }
}

// fused combine + outproj, full-K tiled GEMM (no split-K, no atomics, direct write).
// hidden = [(yf+yb_rev)*silu(z)] @ opw^T. 32x32 tile, K=384 in 8 chunks of 48.
// virtual grid 6x51 = 306.
__device__ void st_outproj(int vb, SMem& sm,
    const float* __restrict__ yraw, const float* __restrict__ xz,
    const float* __restrict__ opw, float* __restrict__ hidden)
{
    if (vb >= 306) return;
    int tid = threadIdx.x;
    int bn = (vb % 6) * 32;
    int bm = (vb / 6) * 32;
    int r0 = (tid >> 4) * 2, c0 = (tid & 15) * 2;
    float acc[2][2] = {};
    for (int k0 = 0; k0 < DI; k0 += 48) {
        // stage A: a[k][row] = (yf+yb)*silu(z); coalesced over k (consecutive channels)
        for (int i = tid; i < 48 * 32; i += 256) {
            int row = i / 48, k = i - row * 48;
            int m = bm + row;
            float vv = 0.f;
            if (m < NTOK) {
                int b = m / LSEQ, t = m % LSEQ;
                int ch = k0 + k;
                float yf = yraw[(size_t)m * DI + ch];
                float yb = yraw[(size_t)(NTOK + b * LSEQ + (LSEQ - 1 - t)) * DI + ch];
                float z  = xz[(size_t)m * (2 * DI) + DI + ch];
                vv = (yf + yb) * silu_f(z);
            }
            sm.op.As[k][row] = vv;
        }
        // stage W: w[k][col] = opw[bn+col][k0+k]; coalesced over k
        for (int i = tid; i < 48 * 32; i += 256) {
            int col = i / 48, k = i - col * 48;
            sm.op.Ws[k][col] = opw[(size_t)(bn + col) * DI + k0 + k];
        }
        __syncthreads();
        #pragma unroll 8
        for (int kk = 0; kk < 48; kk++) {
            float2 av = *(const float2*)&sm.op.As[kk][r0];
            float2 wv = *(const float2*)&sm.op.Ws[kk][c0];
            acc[0][0] += av.x * wv.x; acc[0][1] += av.x * wv.y;
            acc[1][0] += av.y * wv.x; acc[1][1] += av.y * wv.y;
        }
        __syncthreads();
    }
    #pragma unroll
    for (int i = 0; i < 2; i++) {
        int m = bm + r0 + i;
        if (m >= NTOK) continue;
        #pragma unroll
        for (int j = 0; j < 2; j++)
            hidden[(size_t)m * DM + bn + c0 + j] = acc[i][j];
    }
}

// final rmsnorm on token 0 + head (mode-switched output). virtual blocks 0..3.
__device__ void st_final(int vb, SMem& sm,
    const float* __restrict__ residual, const float* __restrict__ hidden,
    const float* __restrict__ norm_f,
    const float* __restrict__ head_w, const float* __restrict__ head_b,
    void* __restrict__ out, const unsigned short* __restrict__ probe)
{
    if (vb >= BATCH) return;
    int b = vb, c = threadIdx.x;
    float r = 0.f;
    if (c < DM) {
        int idx = (b * LSEQ) * DM + c;
        r = residual[idx] + hidden[idx];
    }
    float s = r * r;
    #pragma unroll
    for (int off = 32; off; off >>= 1) s += __shfl_xor(s, off);
    if ((c & 63) == 0) sm.fh.wsum[c >> 6] = s;
    __syncthreads();
    float tot = sm.fh.wsum[0] + sm.fh.wsum[1] + sm.fh.wsum[2] + sm.fh.wsum[3];
    float rms = rsqrtf(tot / (float)DM + 1e-5f);
    if (c < DM) sm.fh.hb[c] = r * rms * norm_f[c];
    __syncthreads();
    if (c < NCLS) {
        float acc = head_b[c];
        #pragma unroll 8
        for (int k = 0; k < DM; k++) acc += sm.fh.hb[k] * head_w[c * DM + k];
        if (probe[0] == 0x3F80u)
            ((__hip_bfloat16*)out)[b * NCLS + c] = __float2bfloat16(acc);
        else
            ((float*)out)[b * NCLS + c] = acc;
    }
}

// ================= persistent megakernel: all 24 layers + head =================
__global__ __launch_bounds__(256, 3) void mamba_layers_k(
    float* __restrict__ resA, float* __restrict__ resB,
    float* __restrict__ hidden, float* __restrict__ hnorm,
    float* __restrict__ xz, float* __restrict__ dbl, float* __restrict__ yraw,
    float* __restrict__ hloc, float* __restrict__ Pc, unsigned* __restrict__ bars,
    const float* __restrict__ norm_w, const float* __restrict__ ipw,
    const float* __restrict__ cw, const float* __restrict__ cb,
    const float* __restrict__ xpw, const float* __restrict__ dtw,
    const float* __restrict__ dtb, const float* __restrict__ A_log,
    const float* __restrict__ A_b_log, const float* __restrict__ Dp,
    const float* __restrict__ opw, const float* __restrict__ norm_f,
    const float* __restrict__ head_w, const float* __restrict__ head_b,
    void* __restrict__ out, const unsigned short* __restrict__ probe)
{
    __shared__ SMem sm;
    int vb = blockIdx.x;
    int slot = 0;
    for (int l = 0; l < DEPTH; l++) {
        const float* rin  = (l & 1) ? resB : resA;
        float*       rout = (l & 1) ? resA : resB;
        st_prenorm(vb, rin, hidden, rout, hnorm, norm_w + (size_t)l * DM, dbl);
        gsync(bars, slot++);
        st_gemm_xz(vb, sm, hnorm, ipw + (size_t)l * 2 * DI * DM, xz);
        gsync(bars, slot++);
        st_xproj(vb, sm, xz, cw + (size_t)l * DI * 4, cb + (size_t)l * DI,
                 xpw + (size_t)l * 44 * DI, dbl);
        gsync(bars, slot++);
        st_scan_part(vb, sm, xz, dbl, cw + (size_t)l * DI * 4, cb + (size_t)l * DI,
                     dtw + (size_t)l * DI * DR, dtb + (size_t)l * DI,
                     A_log + (size_t)l * DI * DS, A_b_log + (size_t)l * DI * DS,
                     hloc, Pc);
        gsync(bars, slot++);
        st_scan_fix(vb, sm, xz, dbl, cw + (size_t)l * DI * 4, cb + (size_t)l * DI,
                    dtw + (size_t)l * DI * DR, dtb + (size_t)l * DI,
                    A_log + (size_t)l * DI * DS, A_b_log + (size_t)l * DI * DS,
                    Dp + (size_t)l * DI, hloc, Pc, yraw);
        gsync(bars, slot++);
        st_outproj(vb, sm, yraw, xz, opw + (size_t)l * DM * DI, hidden);
        gsync(bars, slot++);
    }
    // after layer 23 (odd), rout == resA
    st_final(vb, sm, resA, hidden, norm_f, head_w, head_b, out, probe);
}

extern "C" void kernel_launch(void* const* d_in, const int* in_sizes, int n_in,
                              void* d_out, int out_size, void* d_ws, size_t ws_size,
                              hipStream_t stream)
{
    (void)in_sizes; (void)n_in; (void)out_size; (void)ws_size;
    const float* x      = (const float*)d_in[0];
    const float* pe_w   = (const float*)d_in[1];
    const float* pe_b   = (const float*)d_in[2];
    const float* cls    = (const float*)d_in[3];
    const float* pos    = (const float*)d_in[4];
    const float* norm_w = (const float*)d_in[5];
    const float* ipw    = (const float*)d_in[6];
    const float* cw     = (const float*)d_in[7];
    const float* cb     = (const float*)d_in[8];
    const float* xpw    = (const float*)d_in[9];
    const float* dtw    = (const float*)d_in[10];
    const float* dtb    = (const float*)d_in[11];
    const float* A_log  = (const float*)d_in[12];
    const float* A_b_log= (const float*)d_in[13];
    const float* Dp     = (const float*)d_in[14];
    const float* opw    = (const float*)d_in[15];
    const float* norm_f = (const float*)d_in[16];
    const float* head_w = (const float*)d_in[17];
    const float* head_b = (const float*)d_in[18];
    const unsigned short* probe = (const unsigned short*)d_in[14];

    float* ws = (float*)d_ws;
    const size_t nTokDM = (size_t)NTOK * DM;
    const size_t nTokXZ = (size_t)NTOK * 2 * DI;
    const size_t nDirDI = (size_t)2 * NTOK * DI;
    const size_t nDir44 = (size_t)2 * NTOK * 44;
    const size_t nChunk = (size_t)2 * BATCH * NC * DI * DS;  // 786432
    float* resA   = ws;
    float* resB   = resA + nTokDM;
    float* hidden = resB + nTokDM;
    float* hnorm  = hidden + nTokDM;
    float* xz     = hnorm + nTokDM;
    float* dbl    = xz + nTokXZ;
    float* yraw   = dbl + nDir44;
    float* hloc   = yraw + nDirDI;
    float* Pc     = hloc + nChunk;
    unsigned* bars = (unsigned*)(Pc + nChunk);

    patch_embed_k<<<NTOK / 4, DM, 0, stream>>>(x, pe_w, pe_b, cls, pos, resA, hidden, bars);

    mamba_layers_k<<<NBLK, 256, 0, stream>>>(
        resA, resB, hidden, hnorm, xz, dbl, yraw, hloc, Pc, bars,
        norm_w, ipw, cw, cb, xpw, dtw, dtb, A_log, A_b_log, Dp, opw,
        norm_f, head_w, head_b, d_out, probe);
}

// Round 2
// 6431.310 us; speedup vs baseline: 4.6594x; 4.6594x over previous
//
#include <hip/hip_runtime.h>
#include <hip/hip_bf16.h>

#define DEPTH 24
#define DM 192
#define DI 384
#define DS 16
#define DR 12
#define LSEQ 401
#define BATCH 4
#define NTOK (BATCH*LSEQ)          // 1604
#define NCLS 22
#define SCH 64                     // scan time-chunk staged in LDS

__device__ __forceinline__ float silu_f(float x) { return x / (1.f + __expf(-x)); }

// ---------------- patch embed + cls + pos; 4 tokens per block ----------------
__global__ void patch_embed_k(const float* __restrict__ x,
                              const float* __restrict__ pe_w,
                              const float* __restrict__ pe_b,
                              const float* __restrict__ cls,
                              const float* __restrict__ pos,
                              float* __restrict__ residual, float* __restrict__ hidden)
{
    __shared__ float xp[4][256];
    int g0 = blockIdx.x * 4;
    int c = threadIdx.x;                  // 0..191
    #pragma unroll
    for (int j = 0; j < 4; j++) {
        int g = g0 + j;
        int b = g / LSEQ, t = g % LSEQ;
        if (t != 0) {
            int p = t - 1, pi = p / 200, pj = p % 200;
            for (int i = c; i < 256; i += 192) {
                int pp = i >> 4, qq = i & 15;
                xp[j][i] = x[((size_t)(b * 32 + pi * 16 + pp)) * 3200 + pj * 16 + qq];
            }
        }
    }
    __syncthreads();
    float acc[4] = {0.f, 0.f, 0.f, 0.f};
    for (int k = 0; k < 256; k++) {
        float w = pe_w[c * 256 + k];
        #pragma unroll
        for (int j = 0; j < 4; j++) acc[j] += xp[j][k] * w;
    }
    #pragma unroll
    for (int j = 0; j < 4; j++) {
        int g = g0 + j;
        int t = g % LSEQ;
        float v = (t == 0) ? cls[c] : (acc[j] + pe_b[c]);
        v += pos[t * DM + c];
        residual[(size_t)g * DM + c] = v;
        hidden[(size_t)g * DM + c] = v;
    }
}

// ---------------- fused prenorm + xz GEMM ----------------
// r = resin + hidden (bn==0 blocks write resout=r); rms per row computed in-block;
// xz = (r*rms*nw) @ ipw^T. 64x64 tile, 4x4/thread, K=192 in 4 chunks of 48.
// grid (12, 26) x 256
__global__ __launch_bounds__(256) void gemm_xz_k(
    const float* __restrict__ resin, const float* __restrict__ hidden,
    float* __restrict__ resout, const float* __restrict__ nw,
    const float* __restrict__ ipw, float* __restrict__ xz)
{
    __shared__ float As[48][68];
    __shared__ float Ws[48][68];
    __shared__ float srms[64];
    __shared__ float ps[64][4];
    int tid = threadIdx.x;
    int bn = blockIdx.x * 64;
    int bm = blockIdx.y * 64;
    int rr = tid >> 2, q = tid & 3;          // row 0..63, quarter 0..3
    int m = bm + rr;
    float rv[4][12];                          // this thread's 48 channels of row rr
    float s = 0.f;
    if (m < NTOK) {
        const float* rp = resin + (size_t)m * DM;
        const float* hp = hidden + (size_t)m * DM;
        #pragma unroll
        for (int c = 0; c < 4; c++) {
            int base = c * 48 + q * 12;
            #pragma unroll
            for (int i = 0; i < 12; i += 4) {
                float4 a = *(const float4*)&rp[base + i];
                float4 b = *(const float4*)&hp[base + i];
                float r0 = a.x + b.x, r1 = a.y + b.y, r2 = a.z + b.z, r3 = a.w + b.w;
                rv[c][i] = r0; rv[c][i + 1] = r1; rv[c][i + 2] = r2; rv[c][i + 3] = r3;
                s += r0 * r0 + r1 * r1 + r2 * r2 + r3 * r3;
            }
        }
        if (bn == 0) {
            float* op = resout + (size_t)m * DM;
            #pragma unroll
            for (int c = 0; c < 4; c++) {
                int base = c * 48 + q * 12;
                #pragma unroll
                for (int i = 0; i < 12; i += 4)
                    *(float4*)&op[base + i] =
                        make_float4(rv[c][i], rv[c][i + 1], rv[c][i + 2], rv[c][i + 3]);
            }
        }
    } else {
        #pragma unroll
        for (int c = 0; c < 4; c++)
            #pragma unroll
            for (int i = 0; i < 12; i++) rv[c][i] = 0.f;
    }
    ps[rr][q] = s;
    __syncthreads();
    if (q == 0) {
        float tot = ps[rr][0] + ps[rr][1] + ps[rr][2] + ps[rr][3];
        srms[rr] = rsqrtf(tot * (1.f / (float)DM) + 1e-5f);
    }
    __syncthreads();

    int orow = (tid >> 4) * 4;
    int ocol = (tid & 15) * 4;
    int sk = q * 12;                          // staging K-offset within chunk
    float acc[4][4] = {};
    for (int c = 0; c < 4; c++) {
        float rs = srms[rr];
        #pragma unroll
        for (int i = 0; i < 12; i++)
            As[sk + i][rr] = rv[c][i] * rs * nw[c * 48 + sk + i];
        const float* wp = ipw + (size_t)(bn + rr) * DM + c * 48 + sk;
        #pragma unroll
        for (int i = 0; i < 12; i++)
            Ws[sk + i][rr] = wp[i];
        __syncthreads();
        #pragma unroll
        for (int kk = 0; kk < 48; kk++) {
            float4 a = *(const float4*)&As[kk][orow];
            float4 w = *(const float4*)&Ws[kk][ocol];
            acc[0][0] += a.x * w.x; acc[0][1] += a.x * w.y; acc[0][2] += a.x * w.z; acc[0][3] += a.x * w.w;
            acc[1][0] += a.y * w.x; acc[1][1] += a.y * w.y; acc[1][2] += a.y * w.z; acc[1][3] += a.y * w.w;
            acc[2][0] += a.z * w.x; acc[2][1] += a.z * w.y; acc[2][2] += a.z * w.z; acc[2][3] += a.z * w.w;
            acc[3][0] += a.w * w.x; acc[3][1] += a.w * w.y; acc[3][2] += a.w * w.z; acc[3][3] += a.w * w.w;
        }
        __syncthreads();
    }
    #pragma unroll
    for (int i = 0; i < 4; i++) {
        int mm = bm + orow + i;
        if (mm >= NTOK) continue;
        *(float4*)&xz[(size_t)mm * (2 * DI) + bn + ocol] =
            make_float4(acc[i][0], acc[i][1], acc[i][2], acc[i][3]);
    }
}

// ---------------- xproj, full-K (no atomics, no zeroing) ----------------
// dbl = silu(conv(xz)) @ xpw^T; K=384 in 4 chunks of 96. grid 101 x 256.
__global__ __launch_bounds__(256) void xproj_k(
    const float* __restrict__ xz,
    const float* __restrict__ cw, const float* __restrict__ cb,
    const float* __restrict__ xpw, float* __restrict__ dbl)
{
    __shared__ float As[96][33];
    __shared__ float Ws[96][48];
    int tid = threadIdx.x;
    int bm = blockIdx.x * 32;
    int row = tid & 31, cg = tid >> 5;       // 8 col-groups x 6 cols
    int cbase = cg * 6;
    float acc[6] = {};
    for (int kbase = 0; kbase < DI; kbase += 96) {
        for (int idx = tid; idx < 96 * 32; idx += 256) {
            int k = idx >> 5, r = idx & 31;
            int mm = bm + r;
            float v = 0.f;
            if (mm < 2 * NTOK) {
                int dir = mm / NTOK;
                int rem = mm - dir * NTOK;
                int b = rem / LSEQ, t = rem % LSEQ;
                int ch = kbase + k;
                float a = cb[ch];
                #pragma unroll
                for (int j = 0; j < 4; j++) {
                    int tt = t - 3 + j;
                    if (tt >= 0) {
                        int st = dir ? (LSEQ - 1 - tt) : tt;
                        a += cw[ch * 4 + j] * xz[((size_t)(b * LSEQ + st)) * (2 * DI) + ch];
                    }
                }
                v = silu_f(a);
            }
            As[k][r] = v;
        }
        for (int i = tid; i < 96 * 48; i += 256) {
            int k = i / 48, cc = i % 48;
            Ws[k][cc] = (cc < 44) ? xpw[(size_t)cc * DI + kbase + k] : 0.f;
        }
        __syncthreads();
        #pragma unroll 4
        for (int kk = 0; kk < 96; kk++) {
            float a = As[kk][row];
            #pragma unroll
            for (int j = 0; j < 6; j++) acc[j] += a * Ws[kk][cbase + j];
        }
        __syncthreads();
    }
    int mm = bm + row;
    if (mm < 2 * NTOK) {
        #pragma unroll
        for (int j = 0; j < 6; j++) {
            int cc = cbase + j;
            if (cc < 44) dbl[(size_t)mm * 44 + cc] = acc[j];
        }
    }
}

// ---------------- single-pass selective scan ----------------
// One block per (d-block of 16, db). conv+dt computed once; 401 steps chunked by SCH.
// grid (24, 8) x 256; thread = (dsub 0..15, n 0..15).
__global__ __launch_bounds__(256) void scan_k(
    const float* __restrict__ xz, const float* __restrict__ dbl,
    const float* __restrict__ cw, const float* __restrict__ cb,
    const float* __restrict__ dtw, const float* __restrict__ dtb,
    const float* __restrict__ A_log, const float* __restrict__ A_b_log,
    const float* __restrict__ Dp, float* __restrict__ yraw)
{
    __shared__ float sdbl[SCH][44];
    __shared__ float sxx[SCH][16];
    __shared__ float sdt[SCH][16];
    __shared__ float sy[SCH][16];
    __shared__ float sw[16][12];
    __shared__ float sb2[16];
    int dblk = blockIdx.x;                   // 0..23
    int db = blockIdx.y;                     // 0..7
    int dir = db >> 2, b = db & 3;
    int tid = threadIdx.x;
    int d0 = dblk * 16;
    size_t dof44 = (size_t)db * LSEQ * 44;
    size_t dofD = (size_t)db * LSEQ * DI;
    if (tid < 192) { int d = tid / 12, r = tid - d * 12; sw[d][r] = dtw[(size_t)(d0 + d) * 12 + r]; }
    if (tid < 16) sb2[tid] = dtb[d0 + tid];
    int wave = tid >> 6, lane = tid & 63;
    int dsub = wave * 4 + (lane >> 4);
    int n = lane & 15;
    const float* Al = dir ? A_b_log : A_log;
    float Aval = -__expf(Al[(d0 + dsub) * DS + n]);
    float Dv = Dp[d0 + dsub];
    float h = 0.f;
    for (int t0 = 0; t0 < LSEQ; t0 += SCH) {
        int len = min(LSEQ - t0, SCH);
        for (int i = tid; i < len * 44; i += 256) {
            int t = i / 44, cc = i - t * 44;
            sdbl[t][cc] = dbl[dof44 + (size_t)(t0 + t) * 44 + cc];
        }
        for (int i = tid; i < len * 16; i += 256) {
            int t = i >> 4, d = i & 15;
            int tq = t0 + t, ch = d0 + d;
            float a = cb[ch];
            #pragma unroll
            for (int j = 0; j < 4; j++) {
                int tt = tq - 3 + j;
                if (tt >= 0) {
                    int st = dir ? (LSEQ - 1 - tt) : tt;
                    a += cw[ch * 4 + j] * xz[((size_t)(b * LSEQ + st)) * (2 * DI) + ch];
                }
            }
            sxx[t][d] = silu_f(a);
        }
        __syncthreads();
        for (int i = tid; i < len * 16; i += 256) {
            int t = i >> 4, d = i & 15;
            float a2 = sb2[d];
            #pragma unroll
            for (int r = 0; r < 12; r++) a2 += sdbl[t][r] * sw[d][r];
            sdt[t][d] = (a2 > 15.f) ? a2 : __logf(1.f + __expf(a2));
        }
        __syncthreads();
        #pragma unroll 4
        for (int i = 0; i < len; i++) {
            float dtv = sdt[i][dsub];
            float xv  = sxx[i][dsub];
            float Bv  = sdbl[i][12 + n];
            float Cv  = sdbl[i][28 + n];
            h = __expf(dtv * Aval) * h + (dtv * xv) * Bv;
            float p = h * Cv;
            p += __shfl_xor(p, 1);
            p += __shfl_xor(p, 2);
            p += __shfl_xor(p, 4);
            p += __shfl_xor(p, 8);
            if (n == 0) sy[i][dsub] = p + xv * Dv;
        }
        __syncthreads();
        for (int i = tid; i < len * 16; i += 256) {
            int t = i >> 4, d = i & 15;
            yraw[dofD + (size_t)(t0 + t) * DI + d0 + d] = sy[t][d];
        }
        __syncthreads();
    }
}

// ---------------- fused combine + outproj, full-K, direct write ----------------
// hidden = [(yf+yb_rev)*silu(z)] @ opw^T. 32x32 tile, K=384 in 8 chunks of 48.
// grid (6, 51) x 256
__global__ __launch_bounds__(256) void outproj_k(
    const float* __restrict__ yraw, const float* __restrict__ xz,
    const float* __restrict__ opw, float* __restrict__ hidden)
{
    __shared__ float As[48][34];
    __shared__ float Ws[48][34];
    int tid = threadIdx.x;
    int bn = blockIdx.x * 32;
    int bm = blockIdx.y * 32;
    int orow = (tid >> 4) * 2, ocol = (tid & 15) * 2;
    float acc[2][2] = {};
    for (int k0 = 0; k0 < DI; k0 += 48) {
        for (int i = tid; i < 48 * 32; i += 256) {
            int row = i / 48, k = i - row * 48;
            int mm = bm + row;
            float vv = 0.f;
            if (mm < NTOK) {
                int b = mm / LSEQ, t = mm % LSEQ;
                int ch = k0 + k;
                float yf = yraw[(size_t)mm * DI + ch];
                float yb = yraw[(size_t)(NTOK + b * LSEQ + (LSEQ - 1 - t)) * DI + ch];
                float z  = xz[(size_t)mm * (2 * DI) + DI + ch];
                vv = (yf + yb) * silu_f(z);
            }
            As[k][row] = vv;
        }
        for (int i = tid; i < 48 * 32; i += 256) {
            int col = i / 48, k = i - col * 48;
            Ws[k][col] = opw[(size_t)(bn + col) * DI + k0 + k];
        }
        __syncthreads();
        #pragma unroll 8
        for (int kk = 0; kk < 48; kk++) {
            float2 av = *(const float2*)&As[kk][orow];
            float2 wv = *(const float2*)&Ws[kk][ocol];
            acc[0][0] += av.x * wv.x; acc[0][1] += av.x * wv.y;
            acc[1][0] += av.y * wv.x; acc[1][1] += av.y * wv.y;
        }
        __syncthreads();
    }
    #pragma unroll
    for (int i = 0; i < 2; i++) {
        int mm = bm + orow + i;
        if (mm >= NTOK) continue;
        #pragma unroll
        for (int j = 0; j < 2; j++)
            hidden[(size_t)mm * DM + bn + ocol + j] = acc[i][j];
    }
}

// ---------------- final rmsnorm on token 0 + head (mode-switched output) ----------------
__global__ void final_head_k(const float* __restrict__ residual, const float* __restrict__ hidden,
                             const float* __restrict__ norm_f,
                             const float* __restrict__ head_w,
                             const float* __restrict__ head_b,
                             void* __restrict__ out,
                             const unsigned short* __restrict__ probe)
{
    __shared__ float wsum[3];
    __shared__ float hb[DM];
    int b = blockIdx.x;
    int c = threadIdx.x;
    int idx = (b * LSEQ) * DM + c;
    float r = residual[idx] + hidden[idx];
    float s = r * r;
    for (int off = 32; off > 0; off >>= 1) s += __shfl_down(s, off);
    int wave = c >> 6, lane = c & 63;
    if (lane == 0) wsum[wave] = s;
    __syncthreads();
    float tot = wsum[0] + wsum[1] + wsum[2];
    float rms = rsqrtf(tot / (float)DM + 1e-5f);
    hb[c] = r * rms * norm_f[c];
    __syncthreads();
    if (c < NCLS) {
        float acc = head_b[c];
        #pragma unroll 8
        for (int k = 0; k < DM; k++) acc += hb[k] * head_w[c * DM + k];
        if (probe[0] == 0x3F80u)
            ((__hip_bfloat16*)out)[b * NCLS + c] = __float2bfloat16(acc);
        else
            ((float*)out)[b * NCLS + c] = acc;
    }
}

extern "C" void kernel_launch(void* const* d_in, const int* in_sizes, int n_in,
                              void* d_out, int out_size, void* d_ws, size_t ws_size,
                              hipStream_t stream)
{
    (void)in_sizes; (void)n_in; (void)out_size; (void)ws_size;
    const float* x      = (const float*)d_in[0];
    const float* pe_w   = (const float*)d_in[1];
    const float* pe_b   = (const float*)d_in[2];
    const float* cls    = (const float*)d_in[3];
    const float* pos    = (const float*)d_in[4];
    const float* norm_w = (const float*)d_in[5];
    const float* ipw    = (const float*)d_in[6];
    const float* cw     = (const float*)d_in[7];
    const float* cb     = (const float*)d_in[8];
    const float* xpw    = (const float*)d_in[9];
    const float* dtw    = (const float*)d_in[10];
    const float* dtb    = (const float*)d_in[11];
    const float* A_log  = (const float*)d_in[12];
    const float* A_b_log= (const float*)d_in[13];
    const float* Dp     = (const float*)d_in[14];
    const float* opw    = (const float*)d_in[15];
    const float* norm_f = (const float*)d_in[16];
    const float* head_w = (const float*)d_in[17];
    const float* head_b = (const float*)d_in[18];
    const unsigned short* probe = (const unsigned short*)d_in[14];

    float* ws = (float*)d_ws;
    const size_t nTokDM = (size_t)NTOK * DM;
    const size_t nTokXZ = (size_t)NTOK * 2 * DI;
    const size_t nDirDI = (size_t)2 * NTOK * DI;
    const size_t nDir44 = (size_t)2 * NTOK * 44;
    float* resA   = ws;
    float* resB   = resA + nTokDM;
    float* hidden = resB + nTokDM;
    float* xz     = hidden + nTokDM;
    float* dbl    = xz + nTokXZ;
    float* yraw   = dbl + nDir44;

    patch_embed_k<<<NTOK / 4, DM, 0, stream>>>(x, pe_w, pe_b, cls, pos, resA, hidden);

    for (int l = 0; l < DEPTH; l++) {
        float* rin  = (l & 1) ? resB : resA;
        float* rout = (l & 1) ? resA : resB;

        gemm_xz_k<<<dim3(12, 26), 256, 0, stream>>>(
            rin, hidden, rout, norm_w + (size_t)l * DM,
            ipw + (size_t)l * 2 * DI * DM, xz);

        xproj_k<<<101, 256, 0, stream>>>(
            xz, cw + (size_t)l * DI * 4, cb + (size_t)l * DI,
            xpw + (size_t)l * 44 * DI, dbl);

        scan_k<<<dim3(24, 8), 256, 0, stream>>>(
            xz, dbl, cw + (size_t)l * DI * 4, cb + (size_t)l * DI,
            dtw + (size_t)l * DI * DR, dtb + (size_t)l * DI,
            A_log + (size_t)l * DI * DS, A_b_log + (size_t)l * DI * DS,
            Dp + (size_t)l * DI, yraw);

        outproj_k<<<dim3(6, 51), 256, 0, stream>>>(
            yraw, xz, opw + (size_t)l * DM * DI, hidden);
    }

    final_head_k<<<BATCH, DM, 0, stream>>>(resA, hidden, norm_f, head_w, head_b,
                                           d_out, probe);
}

// Round 3
// 3658.920 us; speedup vs baseline: 8.1899x; 1.7577x over previous
//
#include <hip/hip_runtime.h>
#include <hip/hip_bf16.h>

#define DEPTH 24
#define DM 192
#define DI 384
#define DS 16
#define DR 12
#define LSEQ 401
#define BATCH 4
#define NTOK (BATCH*LSEQ)          // 1604
#define NCLS 22
#define NC 16                      // scan time-chunks
#define TCH 26                     // ceil(401/16); last chunk = 11

__device__ __forceinline__ float silu_f(float x) { return x / (1.f + __expf(-x)); }

// ---------------- patch embed + cls + pos; 4 tokens per block ----------------
__global__ void patch_embed_k(const float* __restrict__ x,
                              const float* __restrict__ pe_w,
                              const float* __restrict__ pe_b,
                              const float* __restrict__ cls,
                              const float* __restrict__ pos,
                              float* __restrict__ residual, float* __restrict__ hidden)
{
    __shared__ float xp[4][256];
    int g0 = blockIdx.x * 4;
    int c = threadIdx.x;                  // 0..191
    #pragma unroll
    for (int j = 0; j < 4; j++) {
        int g = g0 + j;
        int b = g / LSEQ, t = g % LSEQ;
        if (t != 0) {
            int p = t - 1, pi = p / 200, pj = p % 200;
            for (int i = c; i < 256; i += 192) {
                int pp = i >> 4, qq = i & 15;
                xp[j][i] = x[((size_t)(b * 32 + pi * 16 + pp)) * 3200 + pj * 16 + qq];
            }
        }
    }
    __syncthreads();
    float acc[4] = {0.f, 0.f, 0.f, 0.f};
    for (int k = 0; k < 256; k++) {
        float w = pe_w[c * 256 + k];
        #pragma unroll
        for (int j = 0; j < 4; j++) acc[j] += xp[j][k] * w;
    }
    #pragma unroll
    for (int j = 0; j < 4; j++) {
        int g = g0 + j;
        int t = g % LSEQ;
        float v = (t == 0) ? cls[c] : (acc[j] + pe_b[c]);
        v += pos[t * DM + c];
        residual[(size_t)g * DM + c] = v;
        hidden[(size_t)g * DM + c] = v;
    }
}

// ---------------- fused prenorm + xz GEMM (+ dbl zeroing for xproj atomics) ----------------
// r = resin + hidden (bn==0 blocks write resout=r); rms per row computed in-block;
// xz = (r*rms*nw) @ ipw^T. 64x64 tile, 4x4/thread, K=192 in 4 chunks of 48.
// grid (12, 26) x 256
__global__ __launch_bounds__(256) void gemm_xz_k(
    const float* __restrict__ resin, const float* __restrict__ hidden,
    float* __restrict__ resout, const float* __restrict__ nw,
    const float* __restrict__ ipw, float* __restrict__ xz,
    float* __restrict__ dbl)
{
    __shared__ float As[48][68];
    __shared__ float Ws[48][68];
    __shared__ float srms[64];
    __shared__ float ps[64][4];
    int tid = threadIdx.x;
    // zero dbl for the xproj atomics (312 blocks cover 2*NTOK*44 = 141152 floats)
    for (int i = (blockIdx.y * 12 + blockIdx.x) * 256 + tid; i < 2 * NTOK * 44; i += 312 * 256)
        dbl[i] = 0.f;
    int bn = blockIdx.x * 64;
    int bm = blockIdx.y * 64;
    int rr = tid >> 2, q = tid & 3;          // row 0..63, quarter 0..3
    int m = bm + rr;
    float rv[4][12];                          // this thread's 48 channels of row rr
    float s = 0.f;
    if (m < NTOK) {
        const float* rp = resin + (size_t)m * DM;
        const float* hp = hidden + (size_t)m * DM;
        #pragma unroll
        for (int c = 0; c < 4; c++) {
            int base = c * 48 + q * 12;
            #pragma unroll
            for (int i = 0; i < 12; i += 4) {
                float4 a = *(const float4*)&rp[base + i];
                float4 b = *(const float4*)&hp[base + i];
                float r0 = a.x + b.x, r1 = a.y + b.y, r2 = a.z + b.z, r3 = a.w + b.w;
                rv[c][i] = r0; rv[c][i + 1] = r1; rv[c][i + 2] = r2; rv[c][i + 3] = r3;
                s += r0 * r0 + r1 * r1 + r2 * r2 + r3 * r3;
            }
        }
        if (bn == 0) {
            float* op = resout + (size_t)m * DM;
            #pragma unroll
            for (int c = 0; c < 4; c++) {
                int base = c * 48 + q * 12;
                #pragma unroll
                for (int i = 0; i < 12; i += 4)
                    *(float4*)&op[base + i] =
                        make_float4(rv[c][i], rv[c][i + 1], rv[c][i + 2], rv[c][i + 3]);
            }
        }
    } else {
        #pragma unroll
        for (int c = 0; c < 4; c++)
            #pragma unroll
            for (int i = 0; i < 12; i++) rv[c][i] = 0.f;
    }
    ps[rr][q] = s;
    __syncthreads();
    if (q == 0) {
        float tot = ps[rr][0] + ps[rr][1] + ps[rr][2] + ps[rr][3];
        srms[rr] = rsqrtf(tot * (1.f / (float)DM) + 1e-5f);
    }
    __syncthreads();

    int orow = (tid >> 4) * 4;
    int ocol = (tid & 15) * 4;
    int sk = q * 12;                          // staging K-offset within chunk
    float acc[4][4] = {};
    for (int c = 0; c < 4; c++) {
        float rs = srms[rr];
        #pragma unroll
        for (int i = 0; i < 12; i++)
            As[sk + i][rr] = rv[c][i] * rs * nw[c * 48 + sk + i];
        const float* wp = ipw + (size_t)(bn + rr) * DM + c * 48 + sk;
        #pragma unroll
        for (int i = 0; i < 12; i++)
            Ws[sk + i][rr] = wp[i];
        __syncthreads();
        #pragma unroll
        for (int kk = 0; kk < 48; kk++) {
            float4 a = *(const float4*)&As[kk][orow];
            float4 w = *(const float4*)&Ws[kk][ocol];
            acc[0][0] += a.x * w.x; acc[0][1] += a.x * w.y; acc[0][2] += a.x * w.z; acc[0][3] += a.x * w.w;
            acc[1][0] += a.y * w.x; acc[1][1] += a.y * w.y; acc[1][2] += a.y * w.z; acc[1][3] += a.y * w.w;
            acc[2][0] += a.z * w.x; acc[2][1] += a.z * w.y; acc[2][2] += a.z * w.z; acc[2][3] += a.z * w.w;
            acc[3][0] += a.w * w.x; acc[3][1] += a.w * w.y; acc[3][2] += a.w * w.z; acc[3][3] += a.w * w.w;
        }
        __syncthreads();
    }
    #pragma unroll
    for (int i = 0; i < 4; i++) {
        int mm = bm + orow + i;
        if (mm >= NTOK) continue;
        *(float4*)&xz[(size_t)mm * (2 * DI) + bn + ocol] =
            make_float4(acc[i][0], acc[i][1], acc[i][2], acc[i][3]);
    }
}

// ---------------- xproj with conv fused: dbl += silu(conv(xz)) @ xpw^T, split-K=4 ----------------
// grid (4, 101) x 256 — 404 blocks for TLP; atomics into pre-zeroed dbl.
__global__ __launch_bounds__(256) void xproj_conv_k(
    const float* __restrict__ xz,
    const float* __restrict__ cw, const float* __restrict__ cb,
    const float* __restrict__ xpw, float* __restrict__ dbl)
{
    __shared__ float As[96][33];
    __shared__ float Ws[96][48];
    int tid = threadIdx.x;
    int kbase = blockIdx.x * 96;
    int bm = blockIdx.y * 32;
    for (int idx = tid; idx < 96 * 32; idx += 256) {
        int k = idx >> 5, row = idx & 31;
        int m = bm + row;
        float v = 0.f;
        if (m < 2 * NTOK) {
            int dir = m / NTOK;
            int r = m - dir * NTOK;
            int b = r / LSEQ, t = r % LSEQ;
            int ch = kbase + k;
            float a = cb[ch];
            #pragma unroll
            for (int j = 0; j < 4; j++) {
                int tt = t - 3 + j;
                if (tt >= 0) {
                    int st = dir ? (LSEQ - 1 - tt) : tt;
                    a += cw[ch * 4 + j] * xz[((size_t)(b * LSEQ + st)) * (2 * DI) + ch];
                }
            }
            v = silu_f(a);
        }
        As[k][row] = v;
    }
    for (int i = tid; i < 96 * 48; i += 256) {
        int k = i / 48, rr = i % 48;
        Ws[k][rr] = (rr < 44) ? xpw[(size_t)rr * DI + kbase + k] : 0.f;
    }
    __syncthreads();
    int row = tid & 31, cg = tid >> 5;
    int cbase = cg * 6;
    float acc[6] = {};
    #pragma unroll 4
    for (int kk = 0; kk < 96; kk++) {
        float a = As[kk][row];
        #pragma unroll
        for (int j = 0; j < 6; j++) acc[j] += a * Ws[kk][cbase + j];
    }
    int m = bm + row;
    if (m < 2 * NTOK) {
        #pragma unroll
        for (int j = 0; j < 6; j++) {
            int cc = cbase + j;
            if (cc < 44) atomicAdd(&dbl[(size_t)m * 44 + cc], acc[j]);
        }
    }
}

// ---------------- scan pass 1: conv+dt in staging, local scan + chunk product ----------------
// grid (24, NC-1, 8) — all chunks full. 2880 blocks.
__global__ __launch_bounds__(256) void scan_part_k(
    const float* __restrict__ xz, const float* __restrict__ dbl,
    const float* __restrict__ cw, const float* __restrict__ cb,
    const float* __restrict__ dtw, const float* __restrict__ dtb,
    const float* __restrict__ A_log, const float* __restrict__ A_b_log,
    float* __restrict__ hloc, float* __restrict__ Pc)
{
    __shared__ float sdbl[TCH][28];       // pass 1 never reads C (cols 28..43)
    __shared__ float sdt[TCH][16];
    __shared__ float sxx[TCH][16];
    __shared__ float sw[16][12];
    __shared__ float sb2[16];
    int dblk = blockIdx.x, chunk = blockIdx.y;
    int db = blockIdx.z;
    int dir = db >> 2, b = db & 3;
    int tid = threadIdx.x;
    int d0 = dblk * 16;
    int t0 = chunk * TCH;
    size_t dof44 = (size_t)db * LSEQ * 44;
    for (int i = tid; i < TCH * 28; i += 256) {
        int t = i / 28, cc = i - t * 28;
        sdbl[t][cc] = dbl[dof44 + (size_t)(t0 + t) * 44 + cc];
    }
    if (tid < 192) { int d = tid / 12, r = tid - d * 12; sw[d][r] = dtw[(size_t)(d0 + d) * 12 + r]; }
    if (tid < 16) sb2[tid] = dtb[d0 + tid];
    for (int i = tid; i < TCH * 16; i += 256) {
        int t = i >> 4, d = i & 15;
        int tq = t0 + t, ch = d0 + d;
        float a = cb[ch];
        #pragma unroll
        for (int j = 0; j < 4; j++) {
            int tt = tq - 3 + j;
            if (tt >= 0) {
                int st = dir ? (LSEQ - 1 - tt) : tt;
                a += cw[ch * 4 + j] * xz[((size_t)(b * LSEQ + st)) * (2 * DI) + ch];
            }
        }
        sxx[t][d] = silu_f(a);
    }
    __syncthreads();
    for (int i = tid; i < TCH * 16; i += 256) {
        int t = i >> 4, d = i & 15;
        float a2 = sb2[d];
        #pragma unroll
        for (int r = 0; r < 12; r++) a2 += sdbl[t][r] * sw[d][r];
        sdt[t][d] = (a2 > 15.f) ? a2 : __logf(1.f + __expf(a2));
    }
    __syncthreads();
    int wave = tid >> 6, lane = tid & 63;
    int dsub = wave * 4 + (lane >> 4);
    int n = lane & 15;
    const float* Al = dir ? A_b_log : A_log;
    float Aval = -__expf(Al[(d0 + dsub) * DS + n]);
    float h = 0.f, P = 1.f;
    #pragma unroll
    for (int i = 0; i < TCH; i++) {
        float dtv = sdt[i][dsub];
        float xv  = sxx[i][dsub];
        float Bv  = sdbl[i][12 + n];
        float dA = __expf(dtv * Aval);
        h = dA * h + (dtv * xv) * Bv;
        P *= dA;
    }
    size_t idx2 = ((size_t)db * NC + chunk) * (DI * DS) + (size_t)(d0 + dsub) * DS + n;
    hloc[idx2] = h;
    Pc[idx2] = P;
}

// ---------------- scan pass 2: conv+dt in staging, compose h_init, rescan, emit y ----------------
// grid (24, NC, 8) — 3072 blocks.
__global__ __launch_bounds__(256) void scan_fix_k(
    const float* __restrict__ xz, const float* __restrict__ dbl,
    const float* __restrict__ cw, const float* __restrict__ cb,
    const float* __restrict__ dtw, const float* __restrict__ dtb,
    const float* __restrict__ A_log, const float* __restrict__ A_b_log,
    const float* __restrict__ Dp,
    const float* __restrict__ hloc, const float* __restrict__ Pc,
    float* __restrict__ yraw)
{
    __shared__ float sdbl[TCH][44];
    __shared__ float sdt[TCH][16];
    __shared__ float sxx[TCH][16];
    __shared__ float sy[TCH][16];
    __shared__ float sw[16][12];
    __shared__ float sb2[16];
    int dblk = blockIdx.x, chunk = blockIdx.y;
    int db = blockIdx.z;
    int dir = db >> 2, b = db & 3;
    int tid = threadIdx.x;
    int d0 = dblk * 16;
    int t0 = chunk * TCH;
    size_t dofD = (size_t)db * LSEQ * DI;
    size_t dof44 = (size_t)db * LSEQ * 44;
    for (int i = tid; i < TCH * 44; i += 256) {
        int t = i / 44, cc = i - t * 44;
        sdbl[t][cc] = ((t0 + t) < LSEQ) ? dbl[dof44 + (size_t)(t0 + t) * 44 + cc] : 0.f;
    }
    if (tid < 192) { int d = tid / 12, r = tid - d * 12; sw[d][r] = dtw[(size_t)(d0 + d) * 12 + r]; }
    if (tid < 16) sb2[tid] = dtb[d0 + tid];
    for (int i = tid; i < TCH * 16; i += 256) {
        int t = i >> 4, d = i & 15;
        int tq = t0 + t, ch = d0 + d;
        float v = 0.f;
        if (tq < LSEQ) {
            float a = cb[ch];
            #pragma unroll
            for (int j = 0; j < 4; j++) {
                int tt = tq - 3 + j;
                if (tt >= 0) {
                    int st = dir ? (LSEQ - 1 - tt) : tt;
                    a += cw[ch * 4 + j] * xz[((size_t)(b * LSEQ + st)) * (2 * DI) + ch];
                }
            }
            v = silu_f(a);
        }
        sxx[t][d] = v;
    }
    __syncthreads();
    for (int i = tid; i < TCH * 16; i += 256) {
        int t = i >> 4, d = i & 15;
        float a2 = sb2[d];
        #pragma unroll
        for (int r = 0; r < 12; r++) a2 += sdbl[t][r] * sw[d][r];
        sdt[t][d] = (a2 > 15.f) ? a2 : __logf(1.f + __expf(a2));
    }
    __syncthreads();
    int wave = tid >> 6, lane = tid & 63;
    int dsub = wave * 4 + (lane >> 4);
    int n = lane & 15;
    const float* Al = dir ? A_b_log : A_log;
    float Aval = -__expf(Al[(d0 + dsub) * DS + n]);
    float Dv = Dp[d0 + dsub];
    // compose initial state: unconditional loads (always in-bounds), masked combine
    float h = 0.f;
    size_t cbase = (size_t)db * NC * (DI * DS) + (size_t)(d0 + dsub) * DS + n;
    #pragma unroll
    for (int j = 0; j < NC - 1; j++) {
        size_t idx = cbase + (size_t)j * (DI * DS);
        float pj = Pc[idx], hj = hloc[idx];
        h = (j < chunk) ? (pj * h + hj) : h;
    }
    #pragma unroll
    for (int i = 0; i < TCH; i++) {
        float dtv = sdt[i][dsub];
        float xv  = sxx[i][dsub];
        float Bv  = sdbl[i][12 + n];
        float Cv  = sdbl[i][28 + n];
        h = __expf(dtv * Aval) * h + (dtv * xv) * Bv;
        float p = h * Cv;
        p += __shfl_xor(p, 1);
        p += __shfl_xor(p, 2);
        p += __shfl_xor(p, 4);
        p += __shfl_xor(p, 8);
        if (n == 0) sy[i][dsub] = p + xv * Dv;
    }
    __syncthreads();
    int len = min(t0 + TCH, LSEQ) - t0;
    for (int idx = tid; idx < len * 16; idx += 256) {
        int t = idx >> 4, d = idx & 15;
        yraw[dofD + (size_t)(t0 + t) * DI + d0 + d] = sy[t][d];
    }
}

// ---------------- fused combine + outproj, full-K, direct write ----------------
// hidden = [(yf+yb_rev)*silu(z)] @ opw^T. 32x32 tile, K=384 in 8 chunks of 48.
// grid (6, 51) x 256
__global__ __launch_bounds__(256) void outproj_k(
    const float* __restrict__ yraw, const float* __restrict__ xz,
    const float* __restrict__ opw, float* __restrict__ hidden)
{
    __shared__ float As[48][34];
    __shared__ float Ws[48][34];
    int tid = threadIdx.x;
    int bn = blockIdx.x * 32;
    int bm = blockIdx.y * 32;
    int orow = (tid >> 4) * 2, ocol = (tid & 15) * 2;
    float acc[2][2] = {};
    for (int k0 = 0; k0 < DI; k0 += 48) {
        for (int i = tid; i < 48 * 32; i += 256) {
            int row = i / 48, k = i - row * 48;
            int mm = bm + row;
            float vv = 0.f;
            if (mm < NTOK) {
                int b = mm / LSEQ, t = mm % LSEQ;
                int ch = k0 + k;
                float yf = yraw[(size_t)mm * DI + ch];
                float yb = yraw[(size_t)(NTOK + b * LSEQ + (LSEQ - 1 - t)) * DI + ch];
                float z  = xz[(size_t)mm * (2 * DI) + DI + ch];
                vv = (yf + yb) * silu_f(z);
            }
            As[k][row] = vv;
        }
        for (int i = tid; i < 48 * 32; i += 256) {
            int col = i / 48, k = i - col * 48;
            Ws[k][col] = opw[(size_t)(bn + col) * DI + k0 + k];
        }
        __syncthreads();
        #pragma unroll 8
        for (int kk = 0; kk < 48; kk++) {
            float2 av = *(const float2*)&As[kk][orow];
            float2 wv = *(const float2*)&Ws[kk][ocol];
            acc[0][0] += av.x * wv.x; acc[0][1] += av.x * wv.y;
            acc[1][0] += av.y * wv.x; acc[1][1] += av.y * wv.y;
        }
        __syncthreads();
    }
    #pragma unroll
    for (int i = 0; i < 2; i++) {
        int mm = bm + orow + i;
        if (mm >= NTOK) continue;
        #pragma unroll
        for (int j = 0; j < 2; j++)
            hidden[(size_t)mm * DM + bn + ocol + j] = acc[i][j];
    }
}

// ---------------- final rmsnorm on token 0 + head (mode-switched output) ----------------
__global__ void final_head_k(const float* __restrict__ residual, const float* __restrict__ hidden,
                             const float* __restrict__ norm_f,
                             const float* __restrict__ head_w,
                             const float* __restrict__ head_b,
                             void* __restrict__ out,
                             const unsigned short* __restrict__ probe)
{
    __shared__ float wsum[3];
    __shared__ float hb[DM];
    int b = blockIdx.x;
    int c = threadIdx.x;
    int idx = (b * LSEQ) * DM + c;
    float r = residual[idx] + hidden[idx];
    float s = r * r;
    for (int off = 32; off > 0; off >>= 1) s += __shfl_down(s, off);
    int wave = c >> 6, lane = c & 63;
    if (lane == 0) wsum[wave] = s;
    __syncthreads();
    float tot = wsum[0] + wsum[1] + wsum[2];
    float rms = rsqrtf(tot / (float)DM + 1e-5f);
    hb[c] = r * rms * norm_f[c];
    __syncthreads();
    if (c < NCLS) {
        float acc = head_b[c];
        #pragma unroll 8
        for (int k = 0; k < DM; k++) acc += hb[k] * head_w[c * DM + k];
        if (probe[0] == 0x3F80u)
            ((__hip_bfloat16*)out)[b * NCLS + c] = __float2bfloat16(acc);
        else
            ((float*)out)[b * NCLS + c] = acc;
    }
}

extern "C" void kernel_launch(void* const* d_in, const int* in_sizes, int n_in,
                              void* d_out, int out_size, void* d_ws, size_t ws_size,
                              hipStream_t stream)
{
    (void)in_sizes; (void)n_in; (void)out_size; (void)ws_size;
    const float* x      = (const float*)d_in[0];
    const float* pe_w   = (const float*)d_in[1];
    const float* pe_b   = (const float*)d_in[2];
    const float* cls    = (const float*)d_in[3];
    const float* pos    = (const float*)d_in[4];
    const float* norm_w = (const float*)d_in[5];
    const float* ipw    = (const float*)d_in[6];
    const float* cw     = (const float*)d_in[7];
    const float* cb     = (const float*)d_in[8];
    const float* xpw    = (const float*)d_in[9];
    const float* dtw    = (const float*)d_in[10];
    const float* dtb    = (const float*)d_in[11];
    const float* A_log  = (const float*)d_in[12];
    const float* A_b_log= (const float*)d_in[13];
    const float* Dp     = (const float*)d_in[14];
    const float* opw    = (const float*)d_in[15];
    const float* norm_f = (const float*)d_in[16];
    const float* head_w = (const float*)d_in[17];
    const float* head_b = (const float*)d_in[18];
    const unsigned short* probe = (const unsigned short*)d_in[14];

    float* ws = (float*)d_ws;
    const size_t nTokDM = (size_t)NTOK * DM;
    const size_t nTokXZ = (size_t)NTOK * 2 * DI;
    const size_t nDirDI = (size_t)2 * NTOK * DI;
    const size_t nDir44 = (size_t)2 * NTOK * 44;
    const size_t nChunk = (size_t)2 * BATCH * NC * DI * DS;  // 786432
    float* resA   = ws;
    float* resB   = resA + nTokDM;
    float* hidden = resB + nTokDM;
    float* xz     = hidden + nTokDM;
    float* dbl    = xz + nTokXZ;
    float* yraw   = dbl + nDir44;
    float* hloc   = yraw + nDirDI;
    float* Pc     = hloc + nChunk;

    patch_embed_k<<<NTOK / 4, DM, 0, stream>>>(x, pe_w, pe_b, cls, pos, resA, hidden);

    for (int l = 0; l < DEPTH; l++) {
        float* rin  = (l & 1) ? resB : resA;
        float* rout = (l & 1) ? resA : resB;

        gemm_xz_k<<<dim3(12, 26), 256, 0, stream>>>(
            rin, hidden, rout, norm_w + (size_t)l * DM,
            ipw + (size_t)l * 2 * DI * DM, xz, dbl);

        xproj_conv_k<<<dim3(4, 101), 256, 0, stream>>>(
            xz, cw + (size_t)l * DI * 4, cb + (size_t)l * DI,
            xpw + (size_t)l * 44 * DI, dbl);

        scan_part_k<<<dim3(DI / 16, NC - 1, 2 * BATCH), 256, 0, stream>>>(
            xz, dbl, cw + (size_t)l * DI * 4, cb + (size_t)l * DI,
            dtw + (size_t)l * DI * DR, dtb + (size_t)l * DI,
            A_log + (size_t)l * DI * DS, A_b_log + (size_t)l * DI * DS,
            hloc, Pc);

        scan_fix_k<<<dim3(DI / 16, NC, 2 * BATCH), 256, 0, stream>>>(
            xz, dbl, cw + (size_t)l * DI * 4, cb + (size_t)l * DI,
            dtw + (size_t)l * DI * DR, dtb + (size_t)l * DI,
            A_log + (size_t)l * DI * DS, A_b_log + (size_t)l * DI * DS,
            Dp + (size_t)l * DI, hloc, Pc, yraw);

        outproj_k<<<dim3(6, 51), 256, 0, stream>>>(
            yraw, xz, opw + (size_t)l * DM * DI, hidden);
    }

    final_head_k<<<BATCH, DM, 0, stream>>>(resA, hidden, norm_f, head_w, head_b,
                                           d_out, probe);
}

// Round 4
// 3156.393 us; speedup vs baseline: 9.4938x; 1.1592x over previous
//
#include <hip/hip_runtime.h>
#include <hip/hip_bf16.h>

#define DEPTH 24
#define DM 192
#define DI 384
#define DS 16
#define DR 12
#define LSEQ 401
#define BATCH 4
#define NTOK (BATCH*LSEQ)          // 1604
#define NCLS 22
#define NC 16                      // scan time-chunks
#define TCH 26                     // ceil(401/16); last chunk = 11

__device__ __forceinline__ float silu_f(float x) { return x / (1.f + __expf(-x)); }

// ---------------- patch embed + cls + pos; 4 tokens per block ----------------
__global__ void patch_embed_k(const float* __restrict__ x,
                              const float* __restrict__ pe_w,
                              const float* __restrict__ pe_b,
                              const float* __restrict__ cls,
                              const float* __restrict__ pos,
                              float* __restrict__ residual, float* __restrict__ hidden)
{
    __shared__ float xp[4][256];
    int g0 = blockIdx.x * 4;
    int c = threadIdx.x;                  // 0..191
    #pragma unroll
    for (int j = 0; j < 4; j++) {
        int g = g0 + j;
        int b = g / LSEQ, t = g % LSEQ;
        if (t != 0) {
            int p = t - 1, pi = p / 200, pj = p % 200;
            for (int i = c; i < 256; i += 192) {
                int pp = i >> 4, qq = i & 15;
                xp[j][i] = x[((size_t)(b * 32 + pi * 16 + pp)) * 3200 + pj * 16 + qq];
            }
        }
    }
    __syncthreads();
    float acc[4] = {0.f, 0.f, 0.f, 0.f};
    for (int k = 0; k < 256; k++) {
        float w = pe_w[c * 256 + k];
        #pragma unroll
        for (int j = 0; j < 4; j++) acc[j] += xp[j][k] * w;
    }
    #pragma unroll
    for (int j = 0; j < 4; j++) {
        int g = g0 + j;
        int t = g % LSEQ;
        float v = (t == 0) ? cls[c] : (acc[j] + pe_b[c]);
        v += pos[t * DM + c];
        residual[(size_t)g * DM + c] = v;
        hidden[(size_t)g * DM + c] = v;
    }
}

// ---------------- fused prenorm + xz GEMM (+ dbl zeroing for xproj atomics) ----------------
// r = resin + hidden (bn==0 blocks write resout=r); rms per row computed in-block;
// xz = (r*rms*nw) @ ipw^T. 64x64 tile, 4x4/thread, K=192 in 4 chunks of 48.
// grid (12, 26) x 256
__global__ __launch_bounds__(256) void gemm_xz_k(
    const float* __restrict__ resin, const float* __restrict__ hidden,
    float* __restrict__ resout, const float* __restrict__ nw,
    const float* __restrict__ ipw, float* __restrict__ xz,
    float* __restrict__ dbl)
{
    __shared__ float As[48][68];
    __shared__ float Ws[48][68];
    __shared__ float srms[64];
    __shared__ float ps[64][4];
    int tid = threadIdx.x;
    // zero dbl for the xproj atomics (312 blocks cover 2*NTOK*44 = 141152 floats)
    for (int i = (blockIdx.y * 12 + blockIdx.x) * 256 + tid; i < 2 * NTOK * 44; i += 312 * 256)
        dbl[i] = 0.f;
    int bn = blockIdx.x * 64;
    int bm = blockIdx.y * 64;
    int rr = tid >> 2, q = tid & 3;          // row 0..63, quarter 0..3
    int m = bm + rr;
    float rv[4][12];                          // this thread's 48 channels of row rr
    float s = 0.f;
    if (m < NTOK) {
        const float* rp = resin + (size_t)m * DM;
        const float* hp = hidden + (size_t)m * DM;
        #pragma unroll
        for (int c = 0; c < 4; c++) {
            int base = c * 48 + q * 12;
            #pragma unroll
            for (int i = 0; i < 12; i += 4) {
                float4 a = *(const float4*)&rp[base + i];
                float4 b = *(const float4*)&hp[base + i];
                float r0 = a.x + b.x, r1 = a.y + b.y, r2 = a.z + b.z, r3 = a.w + b.w;
                rv[c][i] = r0; rv[c][i + 1] = r1; rv[c][i + 2] = r2; rv[c][i + 3] = r3;
                s += r0 * r0 + r1 * r1 + r2 * r2 + r3 * r3;
            }
        }
        if (bn == 0) {
            float* op = resout + (size_t)m * DM;
            #pragma unroll
            for (int c = 0; c < 4; c++) {
                int base = c * 48 + q * 12;
                #pragma unroll
                for (int i = 0; i < 12; i += 4)
                    *(float4*)&op[base + i] =
                        make_float4(rv[c][i], rv[c][i + 1], rv[c][i + 2], rv[c][i + 3]);
            }
        }
    } else {
        #pragma unroll
        for (int c = 0; c < 4; c++)
            #pragma unroll
            for (int i = 0; i < 12; i++) rv[c][i] = 0.f;
    }
    ps[rr][q] = s;
    __syncthreads();
    if (q == 0) {
        float tot = ps[rr][0] + ps[rr][1] + ps[rr][2] + ps[rr][3];
        srms[rr] = rsqrtf(tot * (1.f / (float)DM) + 1e-5f);
    }
    __syncthreads();

    int orow = (tid >> 4) * 4;
    int ocol = (tid & 15) * 4;
    int sk = q * 12;                          // staging K-offset within chunk
    float acc[4][4] = {};
    for (int c = 0; c < 4; c++) {
        float rs = srms[rr];
        #pragma unroll
        for (int i = 0; i < 12; i++)
            As[sk + i][rr] = rv[c][i] * rs * nw[c * 48 + sk + i];
        const float* wp = ipw + (size_t)(bn + rr) * DM + c * 48 + sk;
        #pragma unroll
        for (int i = 0; i < 12; i++)
            Ws[sk + i][rr] = wp[i];
        __syncthreads();
        #pragma unroll
        for (int kk = 0; kk < 48; kk++) {
            float4 a = *(const float4*)&As[kk][orow];
            float4 w = *(const float4*)&Ws[kk][ocol];
            acc[0][0] += a.x * w.x; acc[0][1] += a.x * w.y; acc[0][2] += a.x * w.z; acc[0][3] += a.x * w.w;
            acc[1][0] += a.y * w.x; acc[1][1] += a.y * w.y; acc[1][2] += a.y * w.z; acc[1][3] += a.y * w.w;
            acc[2][0] += a.z * w.x; acc[2][1] += a.z * w.y; acc[2][2] += a.z * w.z; acc[2][3] += a.z * w.w;
            acc[3][0] += a.w * w.x; acc[3][1] += a.w * w.y; acc[3][2] += a.w * w.z; acc[3][3] += a.w * w.w;
        }
        __syncthreads();
    }
    #pragma unroll
    for (int i = 0; i < 4; i++) {
        int mm = bm + orow + i;
        if (mm >= NTOK) continue;
        *(float4*)&xz[(size_t)mm * (2 * DI) + bn + ocol] =
            make_float4(acc[i][0], acc[i][1], acc[i][2], acc[i][3]);
    }
}

// ---------------- xproj with conv fused: dbl += silu(conv(xz)) @ xpw^T, split-K=4 ----------------
// grid (4, 101) x 256 — 404 blocks for TLP; atomics into pre-zeroed dbl.
// Also zeroes `hidden` for the outproj atomics (gemm_xz has finished reading it).
__global__ __launch_bounds__(256) void xproj_conv_k(
    const float* __restrict__ xz,
    const float* __restrict__ cw, const float* __restrict__ cb,
    const float* __restrict__ xpw, float* __restrict__ dbl,
    float* __restrict__ hidden)
{
    __shared__ float As[96][33];
    __shared__ float Ws[96][48];
    int tid = threadIdx.x;
    // zero hidden (404 blocks cover NTOK*DM = 307968 floats)
    for (int i = (blockIdx.y * 4 + blockIdx.x) * 256 + tid; i < NTOK * DM; i += 404 * 256)
        hidden[i] = 0.f;
    int kbase = blockIdx.x * 96;
    int bm = blockIdx.y * 32;
    for (int idx = tid; idx < 96 * 32; idx += 256) {
        int k = idx >> 5, row = idx & 31;
        int m = bm + row;
        float v = 0.f;
        if (m < 2 * NTOK) {
            int dir = m / NTOK;
            int r = m - dir * NTOK;
            int b = r / LSEQ, t = r % LSEQ;
            int ch = kbase + k;
            float a = cb[ch];
            #pragma unroll
            for (int j = 0; j < 4; j++) {
                int tt = t - 3 + j;
                if (tt >= 0) {
                    int st = dir ? (LSEQ - 1 - tt) : tt;
                    a += cw[ch * 4 + j] * xz[((size_t)(b * LSEQ + st)) * (2 * DI) + ch];
                }
            }
            v = silu_f(a);
        }
        As[k][row] = v;
    }
    for (int i = tid; i < 96 * 48; i += 256) {
        int k = i / 48, rr = i % 48;
        Ws[k][rr] = (rr < 44) ? xpw[(size_t)rr * DI + kbase + k] : 0.f;
    }
    __syncthreads();
    int row = tid & 31, cg = tid >> 5;
    int cbase = cg * 6;
    float acc[6] = {};
    #pragma unroll 4
    for (int kk = 0; kk < 96; kk++) {
        float a = As[kk][row];
        #pragma unroll
        for (int j = 0; j < 6; j++) acc[j] += a * Ws[kk][cbase + j];
    }
    int m = bm + row;
    if (m < 2 * NTOK) {
        #pragma unroll
        for (int j = 0; j < 6; j++) {
            int cc = cbase + j;
            if (cc < 44) atomicAdd(&dbl[(size_t)m * 44 + cc], acc[j]);
        }
    }
}

// ---------------- scan pass 1: conv+dt in staging, local scan + chunk product ----------------
// grid (24, NC-1, 8) — all chunks full. 2880 blocks.
__global__ __launch_bounds__(256) void scan_part_k(
    const float* __restrict__ xz, const float* __restrict__ dbl,
    const float* __restrict__ cw, const float* __restrict__ cb,
    const float* __restrict__ dtw, const float* __restrict__ dtb,
    const float* __restrict__ A_log, const float* __restrict__ A_b_log,
    float* __restrict__ hloc, float* __restrict__ Pc)
{
    __shared__ float sdbl[TCH][28];       // pass 1 never reads C (cols 28..43)
    __shared__ float sdt[TCH][16];
    __shared__ float sxx[TCH][16];
    __shared__ float sw[16][12];
    __shared__ float sb2[16];
    int dblk = blockIdx.x, chunk = blockIdx.y;
    int db = blockIdx.z;
    int dir = db >> 2, b = db & 3;
    int tid = threadIdx.x;
    int d0 = dblk * 16;
    int t0 = chunk * TCH;
    size_t dof44 = (size_t)db * LSEQ * 44;
    for (int i = tid; i < TCH * 28; i += 256) {
        int t = i / 28, cc = i - t * 28;
        sdbl[t][cc] = dbl[dof44 + (size_t)(t0 + t) * 44 + cc];
    }
    if (tid < 192) { int d = tid / 12, r = tid - d * 12; sw[d][r] = dtw[(size_t)(d0 + d) * 12 + r]; }
    if (tid < 16) sb2[tid] = dtb[d0 + tid];
    for (int i = tid; i < TCH * 16; i += 256) {
        int t = i >> 4, d = i & 15;
        int tq = t0 + t, ch = d0 + d;
        float a = cb[ch];
        #pragma unroll
        for (int j = 0; j < 4; j++) {
            int tt = tq - 3 + j;
            if (tt >= 0) {
                int st = dir ? (LSEQ - 1 - tt) : tt;
                a += cw[ch * 4 + j] * xz[((size_t)(b * LSEQ + st)) * (2 * DI) + ch];
            }
        }
        sxx[t][d] = silu_f(a);
    }
    __syncthreads();
    for (int i = tid; i < TCH * 16; i += 256) {
        int t = i >> 4, d = i & 15;
        float a2 = sb2[d];
        #pragma unroll
        for (int r = 0; r < 12; r++) a2 += sdbl[t][r] * sw[d][r];
        sdt[t][d] = (a2 > 15.f) ? a2 : __logf(1.f + __expf(a2));
    }
    __syncthreads();
    int wave = tid >> 6, lane = tid & 63;
    int dsub = wave * 4 + (lane >> 4);
    int n = lane & 15;
    const float* Al = dir ? A_b_log : A_log;
    float Aval = -__expf(Al[(d0 + dsub) * DS + n]);
    float h = 0.f, P = 1.f;
    #pragma unroll
    for (int i = 0; i < TCH; i++) {
        float dtv = sdt[i][dsub];
        float xv  = sxx[i][dsub];
        float Bv  = sdbl[i][12 + n];
        float dA = __expf(dtv * Aval);
        h = dA * h + (dtv * xv) * Bv;
        P *= dA;
    }
    size_t idx2 = ((size_t)db * NC + chunk) * (DI * DS) + (size_t)(d0 + dsub) * DS + n;
    hloc[idx2] = h;
    Pc[idx2] = P;
}

// ---------------- scan pass 2: conv+dt in staging, compose h_init, rescan, emit y ----------------
// grid (24, NC, 8) — 3072 blocks.
__global__ __launch_bounds__(256) void scan_fix_k(
    const float* __restrict__ xz, const float* __restrict__ dbl,
    const float* __restrict__ cw, const float* __restrict__ cb,
    const float* __restrict__ dtw, const float* __restrict__ dtb,
    const float* __restrict__ A_log, const float* __restrict__ A_b_log,
    const float* __restrict__ Dp,
    const float* __restrict__ hloc, const float* __restrict__ Pc,
    float* __restrict__ yraw)
{
    __shared__ float sdbl[TCH][44];
    __shared__ float sdt[TCH][16];
    __shared__ float sxx[TCH][16];
    __shared__ float sy[TCH][16];
    __shared__ float sw[16][12];
    __shared__ float sb2[16];
    int dblk = blockIdx.x, chunk = blockIdx.y;
    int db = blockIdx.z;
    int dir = db >> 2, b = db & 3;
    int tid = threadIdx.x;
    int d0 = dblk * 16;
    int t0 = chunk * TCH;
    size_t dofD = (size_t)db * LSEQ * DI;
    size_t dof44 = (size_t)db * LSEQ * 44;
    for (int i = tid; i < TCH * 44; i += 256) {
        int t = i / 44, cc = i - t * 44;
        sdbl[t][cc] = ((t0 + t) < LSEQ) ? dbl[dof44 + (size_t)(t0 + t) * 44 + cc] : 0.f;
    }
    if (tid < 192) { int d = tid / 12, r = tid - d * 12; sw[d][r] = dtw[(size_t)(d0 + d) * 12 + r]; }
    if (tid < 16) sb2[tid] = dtb[d0 + tid];
    for (int i = tid; i < TCH * 16; i += 256) {
        int t = i >> 4, d = i & 15;
        int tq = t0 + t, ch = d0 + d;
        float v = 0.f;
        if (tq < LSEQ) {
            float a = cb[ch];
            #pragma unroll
            for (int j = 0; j < 4; j++) {
                int tt = tq - 3 + j;
                if (tt >= 0) {
                    int st = dir ? (LSEQ - 1 - tt) : tt;
                    a += cw[ch * 4 + j] * xz[((size_t)(b * LSEQ + st)) * (2 * DI) + ch];
                }
            }
            v = silu_f(a);
        }
        sxx[t][d] = v;
    }
    __syncthreads();
    for (int i = tid; i < TCH * 16; i += 256) {
        int t = i >> 4, d = i & 15;
        float a2 = sb2[d];
        #pragma unroll
        for (int r = 0; r < 12; r++) a2 += sdbl[t][r] * sw[d][r];
        sdt[t][d] = (a2 > 15.f) ? a2 : __logf(1.f + __expf(a2));
    }
    __syncthreads();
    int wave = tid >> 6, lane = tid & 63;
    int dsub = wave * 4 + (lane >> 4);
    int n = lane & 15;
    const float* Al = dir ? A_b_log : A_log;
    float Aval = -__expf(Al[(d0 + dsub) * DS + n]);
    float Dv = Dp[d0 + dsub];
    // compose initial state: unconditional loads (always in-bounds), masked combine
    float h = 0.f;
    size_t cbase = (size_t)db * NC * (DI * DS) + (size_t)(d0 + dsub) * DS + n;
    #pragma unroll
    for (int j = 0; j < NC - 1; j++) {
        size_t idx = cbase + (size_t)j * (DI * DS);
        float pj = Pc[idx], hj = hloc[idx];
        h = (j < chunk) ? (pj * h + hj) : h;
    }
    #pragma unroll
    for (int i = 0; i < TCH; i++) {
        float dtv = sdt[i][dsub];
        float xv  = sxx[i][dsub];
        float Bv  = sdbl[i][12 + n];
        float Cv  = sdbl[i][28 + n];
        h = __expf(dtv * Aval) * h + (dtv * xv) * Bv;
        float p = h * Cv;
        p += __shfl_xor(p, 1);
        p += __shfl_xor(p, 2);
        p += __shfl_xor(p, 4);
        p += __shfl_xor(p, 8);
        if (n == 0) sy[i][dsub] = p + xv * Dv;
    }
    __syncthreads();
    int len = min(t0 + TCH, LSEQ) - t0;
    for (int idx = tid; idx < len * 16; idx += 256) {
        int t = idx >> 4, d = idx & 15;
        yraw[dofD + (size_t)(t0 + t) * DI + d0 + d] = sy[t][d];
    }
}

// ---------------- fused combine + outproj, 2-stage K (baseline-proven) ----------------
// hidden += [(yf+yb_rev)*silu(z)] @ opw^T. 32x32 tile, split-K=2. grid (6, 51, 2).
__global__ __launch_bounds__(256) void outproj_k(
    const float* __restrict__ yraw, const float* __restrict__ xz,
    const float* __restrict__ opw, float* __restrict__ hidden)
{
    __shared__ float As[96][34];
    __shared__ float Ws[96][34];
    int tid = threadIdx.x;
    int bn = blockIdx.x * 32;
    int bm = blockIdx.y * 32;
    int kbase = blockIdx.z * 192;
    int row8 = tid >> 3, seg = tid & 7, k0 = seg * 24;
    float a[24], wreg[24];
    int m = bm + row8;
    if (m < NTOK) {
        int b = m / LSEQ, t = m % LSEQ;
        const float* yf = yraw + (size_t)m * DI + kbase + k0;
        const float* yb = yraw + (size_t)(NTOK + b * LSEQ + (LSEQ - 1 - t)) * DI + kbase + k0;
        const float* zp = xz + (size_t)m * (2 * DI) + DI + kbase + k0;
        #pragma unroll
        for (int i = 0; i < 24; i++) {
            float z = zp[i];
            a[i] = (yf[i] + yb[i]) * (z / (1.f + __expf(-z)));
        }
    } else {
        #pragma unroll
        for (int i = 0; i < 24; i++) a[i] = 0.f;
    }
    {
        const float* wp = opw + (size_t)(bn + row8) * DI + kbase + k0;
        #pragma unroll
        for (int i = 0; i < 24; i++) wreg[i] = wp[i];
    }
    int r0 = (tid >> 4) * 2, c0 = (tid & 15) * 2;
    float acc[2][2] = {};
    #pragma unroll
    for (int st = 0; st < 2; st++) {
        if (st) __syncthreads();
        if ((seg >> 2) == st) {
            int kb = k0 - st * 96;
            #pragma unroll
            for (int i = 0; i < 24; i++) {
                As[kb + i][row8] = a[i];
                Ws[kb + i][row8] = wreg[i];
            }
        }
        __syncthreads();
        #pragma unroll 8
        for (int kk = 0; kk < 96; kk++) {
            float2 av = *(const float2*)&As[kk][r0];
            float2 wv = *(const float2*)&Ws[kk][c0];
            acc[0][0] += av.x * wv.x; acc[0][1] += av.x * wv.y;
            acc[1][0] += av.y * wv.x; acc[1][1] += av.y * wv.y;
        }
    }
    #pragma unroll
    for (int i = 0; i < 2; i++) {
        int mm = bm + r0 + i;
        if (mm >= NTOK) continue;
        #pragma unroll
        for (int j = 0; j < 2; j++)
            atomicAdd(&hidden[(size_t)mm * DM + bn + c0 + j], acc[i][j]);
    }
}

// ---------------- final rmsnorm on token 0 + head (mode-switched output) ----------------
__global__ void final_head_k(const float* __restrict__ residual, const float* __restrict__ hidden,
                             const float* __restrict__ norm_f,
                             const float* __restrict__ head_w,
                             const float* __restrict__ head_b,
                             void* __restrict__ out,
                             const unsigned short* __restrict__ probe)
{
    __shared__ float wsum[3];
    __shared__ float hb[DM];
    int b = blockIdx.x;
    int c = threadIdx.x;
    int idx = (b * LSEQ) * DM + c;
    float r = residual[idx] + hidden[idx];
    float s = r * r;
    for (int off = 32; off > 0; off >>= 1) s += __shfl_down(s, off);
    int wave = c >> 6, lane = c & 63;
    if (lane == 0) wsum[wave] = s;
    __syncthreads();
    float tot = wsum[0] + wsum[1] + wsum[2];
    float rms = rsqrtf(tot / (float)DM + 1e-5f);
    hb[c] = r * rms * norm_f[c];
    __syncthreads();
    if (c < NCLS) {
        float acc = head_b[c];
        #pragma unroll 8
        for (int k = 0; k < DM; k++) acc += hb[k] * head_w[c * DM + k];
        if (probe[0] == 0x3F80u)
            ((__hip_bfloat16*)out)[b * NCLS + c] = __float2bfloat16(acc);
        else
            ((float*)out)[b * NCLS + c] = acc;
    }
}

extern "C" void kernel_launch(void* const* d_in, const int* in_sizes, int n_in,
                              void* d_out, int out_size, void* d_ws, size_t ws_size,
                              hipStream_t stream)
{
    (void)in_sizes; (void)n_in; (void)out_size; (void)ws_size;
    const float* x      = (const float*)d_in[0];
    const float* pe_w   = (const float*)d_in[1];
    const float* pe_b   = (const float*)d_in[2];
    const float* cls    = (const float*)d_in[3];
    const float* pos    = (const float*)d_in[4];
    const float* norm_w = (const float*)d_in[5];
    const float* ipw    = (const float*)d_in[6];
    const float* cw     = (const float*)d_in[7];
    const float* cb     = (const float*)d_in[8];
    const float* xpw    = (const float*)d_in[9];
    const float* dtw    = (const float*)d_in[10];
    const float* dtb    = (const float*)d_in[11];
    const float* A_log  = (const float*)d_in[12];
    const float* A_b_log= (const float*)d_in[13];
    const float* Dp     = (const float*)d_in[14];
    const float* opw    = (const float*)d_in[15];
    const float* norm_f = (const float*)d_in[16];
    const float* head_w = (const float*)d_in[17];
    const float* head_b = (const float*)d_in[18];
    const unsigned short* probe = (const unsigned short*)d_in[14];

    float* ws = (float*)d_ws;
    const size_t nTokDM = (size_t)NTOK * DM;
    const size_t nTokXZ = (size_t)NTOK * 2 * DI;
    const size_t nDirDI = (size_t)2 * NTOK * DI;
    const size_t nDir44 = (size_t)2 * NTOK * 44;
    const size_t nChunk = (size_t)2 * BATCH * NC * DI * DS;  // 786432
    float* resA   = ws;
    float* resB   = resA + nTokDM;
    float* hidden = resB + nTokDM;
    float* xz     = hidden + nTokDM;
    float* dbl    = xz + nTokXZ;
    float* yraw   = dbl + nDir44;
    float* hloc   = yraw + nDirDI;
    float* Pc     = hloc + nChunk;

    patch_embed_k<<<NTOK / 4, DM, 0, stream>>>(x, pe_w, pe_b, cls, pos, resA, hidden);

    for (int l = 0; l < DEPTH; l++) {
        float* rin  = (l & 1) ? resB : resA;
        float* rout = (l & 1) ? resA : resB;

        gemm_xz_k<<<dim3(12, 26), 256, 0, stream>>>(
            rin, hidden, rout, norm_w + (size_t)l * DM,
            ipw + (size_t)l * 2 * DI * DM, xz, dbl);

        xproj_conv_k<<<dim3(4, 101), 256, 0, stream>>>(
            xz, cw + (size_t)l * DI * 4, cb + (size_t)l * DI,
            xpw + (size_t)l * 44 * DI, dbl, hidden);

        scan_part_k<<<dim3(DI / 16, NC - 1, 2 * BATCH), 256, 0, stream>>>(
            xz, dbl, cw + (size_t)l * DI * 4, cb + (size_t)l * DI,
            dtw + (size_t)l * DI * DR, dtb + (size_t)l * DI,
            A_log + (size_t)l * DI * DS, A_b_log + (size_t)l * DI * DS,
            hloc, Pc);

        scan_fix_k<<<dim3(DI / 16, NC, 2 * BATCH), 256, 0, stream>>>(
            xz, dbl, cw + (size_t)l * DI * 4, cb + (size_t)l * DI,
            dtw + (size_t)l * DI * DR, dtb + (size_t)l * DI,
            A_log + (size_t)l * DI * DS, A_b_log + (size_t)l * DI * DS,
            Dp + (size_t)l * DI, hloc, Pc, yraw);

        outproj_k<<<dim3(6, 51, 2), 256, 0, stream>>>(
            yraw, xz, opw + (size_t)l * DM * DI, hidden);
    }

    final_head_k<<<BATCH, DM, 0, stream>>>(resA, hidden, norm_f, head_w, head_b,
                                           d_out, probe);
}